// Round 2
// baseline (3670.488 us; speedup 1.0000x reference)
//
#include <hip/hip_runtime.h>
#include <math.h>

#define S_LEN 128
#define D_MODEL 512
#define B_SZ 256
#define NHEADS 8
#define HD 64
#define DFFN 2048
#define PI_D 3.14159265358979323846

// ---------------- GEMM: C[M,N] = A[M,K] @ W[N,K]^T + bias, optional ReLU ----
// 128x128 tile, BK=8, 256 threads, 8x8 per thread. Requires M%128==0, N%128==0, K%8==0.
template<int RELU>
__global__ __launch_bounds__(256) void gemm_bias(const float* __restrict__ A,
        const float* __restrict__ W, const float* __restrict__ bias,
        float* __restrict__ C, int M, int N, int K)
{
    __shared__ float As[8][128];
    __shared__ float Ws[8][128];
    const int tid = threadIdx.x;
    const int tn = tid & 15, tm = tid >> 4;
    const int row0 = blockIdx.y * 128, col0 = blockIdx.x * 128;
    const int lr = tid >> 1, lc = (tid & 1) * 4;
    const float* Ap = A + (size_t)(row0 + lr) * K + lc;
    const float* Wp = W + (size_t)(col0 + lr) * K + lc;
    float acc[8][8];
#pragma unroll
    for (int i = 0; i < 8; ++i)
#pragma unroll
        for (int j = 0; j < 8; ++j) acc[i][j] = 0.f;

    for (int k0 = 0; k0 < K; k0 += 8) {
        float4 av = *(const float4*)(Ap + k0);
        float4 wv = *(const float4*)(Wp + k0);
        __syncthreads();
        As[lc + 0][lr] = av.x; As[lc + 1][lr] = av.y;
        As[lc + 2][lr] = av.z; As[lc + 3][lr] = av.w;
        Ws[lc + 0][lr] = wv.x; Ws[lc + 1][lr] = wv.y;
        Ws[lc + 2][lr] = wv.z; Ws[lc + 3][lr] = wv.w;
        __syncthreads();
#pragma unroll
        for (int k = 0; k < 8; ++k) {
            float ar[8], wr[8];
#pragma unroll
            for (int i = 0; i < 8; ++i) ar[i] = As[k][tm * 8 + i];
#pragma unroll
            for (int j = 0; j < 8; ++j) wr[j] = Ws[k][tn * 8 + j];
#pragma unroll
            for (int i = 0; i < 8; ++i)
#pragma unroll
                for (int j = 0; j < 8; ++j)
                    acc[i][j] = fmaf(ar[i], wr[j], acc[i][j]);
        }
    }
#pragma unroll
    for (int i = 0; i < 8; ++i) {
        const int r = row0 + tm * 8 + i;
#pragma unroll
        for (int j = 0; j < 8; ++j) {
            const int c = col0 + tn * 8 + j;
            float v = acc[i][j] + bias[c];
            if (RELU) v = fmaxf(v, 0.f);
            C[(size_t)r * N + c] = v;
        }
    }
}

// ---------------- Attention: one block per (b,h), one thread per query row --
__global__ __launch_bounds__(128) void attn_kernel(const float* __restrict__ qkv,
                                                   float* __restrict__ o)
{
    const int bh = blockIdx.x;
    const int b = bh >> 3, hh = bh & 7;
    const int t = threadIdx.x;  // query row 0..127
    __shared__ float Ks[S_LEN][HD];
    __shared__ float Vs[S_LEN][HD];
    const float* base = qkv + (size_t)b * S_LEN * (3 * D_MODEL);
    const float* krow = base + (size_t)t * (3 * D_MODEL) + D_MODEL + hh * HD;
    const float* vrow = base + (size_t)t * (3 * D_MODEL) + 2 * D_MODEL + hh * HD;
#pragma unroll
    for (int d = 0; d < HD; d += 4) {
        *(float4*)&Ks[t][d] = *(const float4*)(krow + d);
        *(float4*)&Vs[t][d] = *(const float4*)(vrow + d);
    }
    float q[HD];
    const float* qrow = base + (size_t)t * (3 * D_MODEL) + hh * HD;
#pragma unroll
    for (int d = 0; d < HD; d += 4) {
        float4 v4 = *(const float4*)(qrow + d);
        q[d] = v4.x; q[d + 1] = v4.y; q[d + 2] = v4.z; q[d + 3] = v4.w;
    }
    __syncthreads();
    float m = -1e30f, l = 0.f;
    float oacc[HD];
#pragma unroll
    for (int d = 0; d < HD; ++d) oacc[d] = 0.f;
    for (int j = 0; j < S_LEN; ++j) {
        float s = 0.f;
#pragma unroll
        for (int d = 0; d < HD; ++d) s = fmaf(q[d], Ks[j][d], s);
        s *= 0.125f;
        const float nm = fmaxf(m, s);
        const float sc = expf(m - nm);
        const float p = expf(s - nm);
        l = l * sc + p;
#pragma unroll
        for (int d = 0; d < HD; ++d) oacc[d] = oacc[d] * sc + p * Vs[j][d];
        m = nm;
    }
    const float inv = 1.f / l;
    float* orow = o + (size_t)b * S_LEN * D_MODEL + (size_t)t * D_MODEL + hh * HD;
#pragma unroll
    for (int d = 0; d < HD; ++d) orow[d] = oacc[d] * inv;
}

// ---------------- residual add + LayerNorm (row of 512), 128 threads -------
__global__ __launch_bounds__(128) void add_ln_kernel(const float* __restrict__ a,
        const float* __restrict__ bb, const float* __restrict__ g,
        const float* __restrict__ be, float* __restrict__ out)
{
    __shared__ float red[2];
    const int row = blockIdx.x, t = threadIdx.x;
    float4 av = *(const float4*)(a + (size_t)row * D_MODEL + t * 4);
    float4 bv = *(const float4*)(bb + (size_t)row * D_MODEL + t * 4);
    float x0 = av.x + bv.x, x1 = av.y + bv.y, x2 = av.z + bv.z, x3 = av.w + bv.w;
    float ssum = x0 + x1 + x2 + x3;
#pragma unroll
    for (int off = 32; off >= 1; off >>= 1) ssum += __shfl_xor(ssum, off);
    if ((t & 63) == 0) red[t >> 6] = ssum;
    __syncthreads();
    const float mean = (red[0] + red[1]) * (1.f / 512.f);
    __syncthreads();
    float d0 = x0 - mean, d1 = x1 - mean, d2 = x2 - mean, d3 = x3 - mean;
    float sq = d0 * d0 + d1 * d1 + d2 * d2 + d3 * d3;
#pragma unroll
    for (int off = 32; off >= 1; off >>= 1) sq += __shfl_xor(sq, off);
    if ((t & 63) == 0) red[t >> 6] = sq;
    __syncthreads();
    const float var = (red[0] + red[1]) * (1.f / 512.f);
    const float inv = 1.0f / sqrtf(var + 1e-5f);
    float4 gv = *(const float4*)(g + t * 4);
    float4 bev = *(const float4*)(be + t * 4);
    float4 ov = make_float4(d0 * inv * gv.x + bev.x, d1 * inv * gv.y + bev.y,
                            d2 * inv * gv.z + bev.z, d3 * inv * gv.w + bev.w);
    *(float4*)(out + (size_t)row * D_MODEL + t * 4) = ov;
}

// ---------------- mean over sequence (one block per batch elem in chunk) ----
__global__ __launch_bounds__(128) void pool_kernel(const float* __restrict__ x,
                                                   float* __restrict__ pooled)
{
    const int b = blockIdx.x, t = threadIdx.x;
    float4 acc = make_float4(0.f, 0.f, 0.f, 0.f);
    const float* base = x + (size_t)b * S_LEN * D_MODEL + t * 4;
    for (int s = 0; s < S_LEN; ++s) {
        float4 v = *(const float4*)(base + (size_t)s * D_MODEL);
        acc.x += v.x; acc.y += v.y; acc.z += v.z; acc.w += v.w;
    }
    const float sc = 1.f / 128.f;
    float4 ov = make_float4(acc.x * sc, acc.y * sc, acc.z * sc, acc.w * sc);
    *(float4*)(pooled + (size_t)b * D_MODEL + t * 4) = ov;
}

// ---------------- root-MUSIC: one 64-lane block per (batch, x/y) -----------
__global__ __launch_bounds__(64) void music_kernel(const float* __restrict__ RxRy,
                                                   float* __restrict__ hbuf)
{
    const int pb = blockIdx.x;          // 0..511
    const int b = pb >> 1, which = pb & 1;
    const float* src = RxRy + (size_t)which * (B_SZ * 128) + (size_t)b * 128;
    const int t = threadIdx.x;

    __shared__ double KRe[8][8], KIm[8][8];
    __shared__ double Are[8][8], Aim[8][8];
    __shared__ double Vre[8][8], Vim[8][8];
    __shared__ double Fre[8][8], Fim[8][8];
    __shared__ double rot[4];
    __shared__ double cr[15], ci[15];
    __shared__ double br[14], bi[14];
    __shared__ double zr[14], zi[14];
    __shared__ int topidx[3];

    {   // load K = complex(Rx[:8], Rx[8:])
        const int i = t >> 3, j = t & 7;
        KRe[i][j] = (double)src[i * 8 + j];
        KIm[i][j] = (double)src[64 + i * 8 + j];
    }
    __syncthreads();
    {   // Rz = K^H K + I ; V = I
        const int i = t >> 3, k = t & 7;
        double sre = (i == k) ? 1.0 : 0.0, sim = 0.0;
        for (int j = 0; j < 8; ++j) {
            const double ar = KRe[j][i], ai = KIm[j][i];
            const double xr = KRe[j][k], xi = KIm[j][k];
            sre += ar * xr + ai * xi;
            sim += ar * xi - ai * xr;
        }
        Are[i][k] = sre; Aim[i][k] = sim;
        Vre[i][k] = (i == k) ? 1.0 : 0.0;
        Vim[i][k] = 0.0;
    }
    __syncthreads();

    // cyclic complex Jacobi, 9 sweeps
    for (int sweep = 0; sweep < 9; ++sweep) {
        for (int p = 0; p < 7; ++p) {
            for (int q = p + 1; q < 8; ++q) {
                if (t == 0) {
                    const double gre = Are[p][q], gim = Aim[p][q];
                    const double r = sqrt(gre * gre + gim * gim);
                    if (r < 1e-60) {
                        rot[0] = 1.0; rot[1] = 0.0; rot[2] = 1.0; rot[3] = 0.0;
                    } else {
                        const double tau = (Are[p][p] - Are[q][q]) / (2.0 * r);
                        const double tt = ((tau >= 0.0) ? 1.0 : -1.0) /
                                          (fabs(tau) + sqrt(1.0 + tau * tau));
                        const double c = 1.0 / sqrt(1.0 + tt * tt);
                        rot[0] = c; rot[1] = tt * c; rot[2] = gre / r; rot[3] = gim / r;
                    }
                }
                __syncthreads();
                const double c = rot[0], s = rot[1], er = rot[2], ei = rot[3];
                if (t < 8) {  // column update on A and V  (A <- A U, V <- V U)
                    const int k = t;
                    double apr = Are[k][p], api = Aim[k][p];
                    double aqr = Are[k][q], aqi = Aim[k][q];
                    Are[k][p] = c * apr + s * (er * aqr + ei * aqi);
                    Aim[k][p] = c * api + s * (er * aqi - ei * aqr);
                    Are[k][q] = c * aqr - s * (er * apr - ei * api);
                    Aim[k][q] = c * aqi - s * (er * api + ei * apr);
                    double vpr = Vre[k][p], vpi = Vim[k][p];
                    double vqr = Vre[k][q], vqi = Vim[k][q];
                    Vre[k][p] = c * vpr + s * (er * vqr + ei * vqi);
                    Vim[k][p] = c * vpi + s * (er * vqi - ei * vqr);
                    Vre[k][q] = c * vqr - s * (er * vpr - ei * vpi);
                    Vim[k][q] = c * vqi - s * (er * vpi + ei * vpr);
                }
                __syncthreads();
                if (t < 8) {  // row update (A <- U^H A)
                    const int k = t;
                    double apr = Are[p][k], api = Aim[p][k];
                    double aqr = Are[q][k], aqi = Aim[q][k];
                    Are[p][k] = c * apr + s * (er * aqr - ei * aqi);
                    Aim[p][k] = c * api + s * (er * aqi + ei * aqr);
                    Are[q][k] = c * aqr - s * (er * apr + ei * api);
                    Aim[q][k] = c * aqi - s * (er * api - ei * apr);
                }
                __syncthreads();
                if (t == 0) {
                    Are[p][q] = 0.0; Aim[p][q] = 0.0;
                    Are[q][p] = 0.0; Aim[q][p] = 0.0;
                    Aim[p][p] = 0.0; Aim[q][q] = 0.0;
                }
                __syncthreads();
            }
        }
    }

    if (t == 0) {  // indices of 3 largest eigenvalues (signal subspace)
        bool used[8] = {false, false, false, false, false, false, false, false};
        for (int tt = 0; tt < 3; ++tt) {
            double best = -1e300; int bidx = 0;
            for (int i = 0; i < 8; ++i)
                if (!used[i] && Are[i][i] > best) { best = Are[i][i]; bidx = i; }
            used[bidx] = true; topidx[tt] = bidx;
        }
    }
    __syncthreads();
    {   // F = I - sum_top3 v v^H  (noise projector)
        const int i = t >> 3, j = t & 7;
        double fre = (i == j) ? 1.0 : 0.0, fim = 0.0;
        for (int tt = 0; tt < 3; ++tt) {
            const int e = topidx[tt];
            const double vir = Vre[i][e], vii = Vim[i][e];
            const double vjr = Vre[j][e], vji = Vim[j][e];
            fre -= vir * vjr + vii * vji;
            fim -= vii * vjr - vir * vji;
        }
        Fre[i][j] = fre; Fim[i][j] = fim;
    }
    __syncthreads();
    if (t < 15) {  // coeffs: sum of diagonal at offset o = t-7  (F[r][r+o])
        const int o = t - 7;
        double sre = 0.0, sim = 0.0;
        for (int r = 0; r < 8; ++r) {
            const int cc = r + o;
            if (cc >= 0 && cc < 8) { sre += Fre[r][cc]; sim += Fim[r][cc]; }
        }
        cr[t] = sre; ci[t] = sim;
    }
    __syncthreads();
    if (t < 14) {  // monic normalize + init roots (0.4+0.9i)^(t+1)
        const double den = cr[0] * cr[0] + ci[0] * ci[0];
        const double nr = cr[t + 1], ni = ci[t + 1];
        br[t] = (nr * cr[0] + ni * ci[0]) / den;
        bi[t] = (ni * cr[0] - nr * ci[0]) / den;
        double zre_ = 1.0, zim_ = 0.0;
        for (int k = 0; k <= t; ++k) {
            const double a2 = zre_ * 0.4 - zim_ * 0.9;
            zim_ = zre_ * 0.9 + zim_ * 0.4;
            zre_ = a2;
        }
        zr[t] = zre_; zi[t] = zim_;
    }
    __syncthreads();
    for (int it = 0; it < 128; ++it) {  // Durand-Kerner, synchronous update
        double nzr = 0.0, nzi = 0.0;
        if (t < 14) {
            const double zre_ = zr[t], zim_ = zi[t];
            double wre = 1.0, wim = 0.0;  // monic Horner
            for (int j = 0; j < 14; ++j) {
                const double tr = wre * zre_ - wim * zim_ + br[j];
                wim = wre * zim_ + wim * zre_ + bi[j];
                wre = tr;
            }
            double dre = 1.0, dim = 0.0;
            for (int j = 0; j < 14; ++j) {
                if (j == t) continue;
                const double exr = zre_ - zr[j], exi = zim_ - zi[j];
                const double tr = dre * exr - dim * exi;
                dim = dre * exi + dim * exr;
                dre = tr;
            }
            const double dd = dre * dre + dim * dim;
            if (dd > 1e-260) {
                const double qre = (wre * dre + wim * dim) / dd;
                const double qim = (wim * dre - wre * dim) / dd;
                nzr = zre_ - qre; nzi = zim_ - qim;
            } else {
                nzr = zre_ + 1e-8; nzi = zim_ - 1e-8;
            }
        }
        __syncthreads();
        if (t < 14) { zr[t] = nzr; zi[t] = nzi; }
        __syncthreads();
    }
    if (t == 0) {  // keyv selection (3 smallest, stable on ties) -> doa
        double keyv[14]; bool used[14];
        for (int i = 0; i < 14; ++i) {
            const double mag = sqrt(zr[i] * zr[i] + zi[i] * zi[i]);
            keyv[i] = fabs(mag - 1.0) + ((mag < 1.0) ? 0.0 : 1e6);
            used[i] = false;
        }
        for (int tt = 0; tt < 3; ++tt) {
            double best = 1e300; int bidx = 0;
            for (int i = 0; i < 14; ++i)
                if (!used[i] && keyv[i] < best) { best = keyv[i]; bidx = i; }
            used[bidx] = true;
            const double ang = atan2(zi[bidx], zr[bidx]);
            double ratio = ang / PI_D;
            if (ratio > 1.0) ratio = 1.0;
            if (ratio < -1.0) ratio = -1.0;
            hbuf[(size_t)b * 6 + which * 3 + tt] = (float)asin(ratio);
        }
    }
}

// ---------------- final MLP 6->256->256->6, one block per batch ------------
__global__ __launch_bounds__(256) void mlp_kernel(const float* __restrict__ hbuf,
        const float* __restrict__ w1, const float* __restrict__ b1,
        const float* __restrict__ w2, const float* __restrict__ b2,
        const float* __restrict__ w3, const float* __restrict__ b3,
        float* __restrict__ outp)
{
    const int b = blockIdx.x, t = threadIdx.x;
    __shared__ float hin[8];
    __shared__ float h1[256];
    __shared__ float h2[256];
    if (t < 6) hin[t] = hbuf[b * 6 + t];
    __syncthreads();
    float acc = b1[t];
#pragma unroll
    for (int k = 0; k < 6; ++k) acc += hin[k] * w1[t * 6 + k];
    h1[t] = fmaxf(acc, 0.f);
    __syncthreads();
    float acc2 = b2[t];
    for (int k = 0; k < 256; ++k) acc2 += h1[k] * w2[t * 256 + k];
    h2[t] = fmaxf(acc2, 0.f);
    __syncthreads();
    if (t < 6) {
        float acc3 = b3[t];
        for (int k = 0; k < 256; ++k) acc3 += h2[k] * w3[t * 256 + k];
        if (t < 3) outp[b * 3 + t] = acc3;
        else       outp[B_SZ * 3 + b * 3 + (t - 3)] = acc3;
    }
}

// ---------------- host launcher --------------------------------------------
extern "C" void kernel_launch(void* const* d_in, const int* in_sizes, int n_in,
                              void* d_out, int out_size, void* d_ws, size_t ws_size,
                              hipStream_t stream)
{
    const float* x_in      = (const float*)d_in[0];   // (256,128,32,16) == (32768,512)
    const float* in_proj_w = (const float*)d_in[1];
    const float* in_proj_b = (const float*)d_in[2];
    const float* out_proj_w= (const float*)d_in[3];
    const float* out_proj_b= (const float*)d_in[4];
    const float* ln1_g     = (const float*)d_in[5];
    const float* ln1_b     = (const float*)d_in[6];
    const float* ffn_w1    = (const float*)d_in[7];
    const float* ffn_b1    = (const float*)d_in[8];
    const float* ffn_w2    = (const float*)d_in[9];
    const float* ffn_b2    = (const float*)d_in[10];
    const float* ln2_g     = (const float*)d_in[11];
    const float* ln2_b     = (const float*)d_in[12];
    const float* fcx_w     = (const float*)d_in[13];
    const float* fcx_b     = (const float*)d_in[14];
    const float* fcy_w     = (const float*)d_in[15];
    const float* fcy_b     = (const float*)d_in[16];
    const float* mlp_w1    = (const float*)d_in[17];
    const float* mlp_b1    = (const float*)d_in[18];
    const float* mlp_w2    = (const float*)d_in[19];
    const float* mlp_b2    = (const float*)d_in[20];
    const float* mlp_w3    = (const float*)d_in[21];
    const float* mlp_b3    = (const float*)d_in[22];

    // ---- adaptive chunking over the batch to fit d_ws --------------------
    // footprint(floats) = 393216*c (RA 262144c | x1 65536c | ff2 65536c)
    //                     + 262144 (pooled + RxRy + hbuf + slack)
    const size_t ws_floats = ws_size / sizeof(float);
    int c = 256;
    while (c > 1 && (size_t)393216 * (size_t)c + 262144 > ws_floats) c >>= 1;

    float* ws = (float*)d_ws;
    float* RA     = ws;                               // 262144*c : qkv | ff1
    float* x1     = RA + (size_t)262144 * c;          // 65536*c
    float* ff2    = x1 + (size_t)65536 * c;           // 65536*c
    float* pooled = ff2 + (size_t)65536 * c;          // 131072
    float* RxRy   = pooled + 131072;                  // 65536
    float* hbuf   = RxRy + 65536;                     // 1536

    float* qkv = RA;                                  // 196608*c
    float* o   = RA + (size_t)196608 * c;             // 65536*c (overlaid by ff1)
    float* ff1 = RA;                                  // 262144*c

    for (int b0 = 0; b0 < B_SZ; b0 += c) {
        const int Tc = c * S_LEN;                     // tokens in chunk
        const float* xc = x_in + (size_t)b0 * S_LEN * D_MODEL;

        // 1. qkv = x @ Wi^T + bi
        gemm_bias<0><<<dim3(1536 / 128, Tc / 128), 256, 0, stream>>>(
            xc, in_proj_w, in_proj_b, qkv, Tc, 3 * D_MODEL, D_MODEL);
        // 2. attention
        attn_kernel<<<c * NHEADS, 128, 0, stream>>>(qkv, o);
        // 3. out proj
        gemm_bias<0><<<dim3(512 / 128, Tc / 128), 256, 0, stream>>>(
            o, out_proj_w, out_proj_b, x1, Tc, D_MODEL, D_MODEL);
        // 4. x1 = LN(x + proj)   (in place over x1)
        add_ln_kernel<<<Tc, 128, 0, stream>>>(xc, x1, ln1_g, ln1_b, x1);
        // 5. ff1 = relu(x1 @ W1^T + b1)   (overlays dead qkv+o)
        gemm_bias<1><<<dim3(DFFN / 128, Tc / 128), 256, 0, stream>>>(
            x1, ffn_w1, ffn_b1, ff1, Tc, DFFN, D_MODEL);
        // 6. ff2 = ff1 @ W2^T + b2
        gemm_bias<0><<<dim3(512 / 128, Tc / 128), 256, 0, stream>>>(
            ff1, ffn_w2, ffn_b2, ff2, Tc, D_MODEL, DFFN);
        // 7. x2 = LN(x1 + ff2)   (in place over x1)
        add_ln_kernel<<<Tc, 128, 0, stream>>>(x1, ff2, ln2_g, ln2_b, x1);
        // 8. mean pool into the full-size pooled buffer
        pool_kernel<<<c, 128, 0, stream>>>(x1, pooled + (size_t)b0 * D_MODEL);
    }

    // 9. heads (full batch: M=256)
    gemm_bias<0><<<dim3(1, 2), 256, 0, stream>>>(
        pooled, fcx_w, fcx_b, RxRy, B_SZ, 128, D_MODEL);
    gemm_bias<0><<<dim3(1, 2), 256, 0, stream>>>(
        pooled, fcy_w, fcy_b, RxRy + B_SZ * 128, B_SZ, 128, D_MODEL);
    // 10. root-MUSIC (fp64)
    music_kernel<<<2 * B_SZ, 64, 0, stream>>>(RxRy, hbuf);
    // 11. final MLP
    mlp_kernel<<<B_SZ, 256, 0, stream>>>(hbuf, mlp_w1, mlp_b1, mlp_w2, mlp_b2,
                                         mlp_w3, mlp_b3, (float*)d_out);
}

// Round 3
// 1722.711 us; speedup vs baseline: 2.1306x; 2.1306x over previous
//
#include <hip/hip_runtime.h>
#include <math.h>

#define S_LEN 128
#define D_MODEL 512
#define B_SZ 256
#define NHEADS 8
#define HD 64
#define DFFN 2048
#define PI_D 3.14159265358979323846

typedef _Float16 f16x8 __attribute__((ext_vector_type(8)));
typedef _Float16 f16x4 __attribute__((ext_vector_type(4)));
typedef float f32x4 __attribute__((ext_vector_type(4)));

// ---------------- weight split: fp32 -> (hi, lo) fp16 ----------------------
__global__ __launch_bounds__(256) void cvt_split(const float* __restrict__ in,
        _Float16* __restrict__ hi, _Float16* __restrict__ lo, int n4)
{
    const int i = blockIdx.x * 256 + threadIdx.x;
    if (i >= n4) return;
    float4 v = ((const float4*)in)[i];
    f16x4 h, l;
    _Float16 h0 = (_Float16)v.x; h[0] = h0; l[0] = (_Float16)(v.x - (float)h0);
    _Float16 h1 = (_Float16)v.y; h[1] = h1; l[1] = (_Float16)(v.y - (float)h1);
    _Float16 h2 = (_Float16)v.z; h[2] = h2; l[2] = (_Float16)(v.z - (float)h2);
    _Float16 h3 = (_Float16)v.w; h[3] = h3; l[3] = (_Float16)(v.w - (float)h3);
    ((f16x4*)hi)[i] = h;
    ((f16x4*)lo)[i] = l;
}

// ---------------- MFMA GEMM: C[M,N] = A[M,K](fp32) @ W[N,K]^T + bias -------
// fp16 two-term split, 3 MFMA passes (hi*hi + hi*lo + lo*hi), fp32 accum.
// 128x128 tile, BK=64, 256 threads = 4 waves (2x2), 16x16x32 f16 MFMA.
// Requires M%128==0, N%128==0, K%64==0.
template<int RELU>
__global__ __launch_bounds__(256) void gemm_mfma(const float* __restrict__ A,
        const _Float16* __restrict__ Whg, const _Float16* __restrict__ Wlg,
        const float* __restrict__ bias, float* __restrict__ C,
        int M, int N, int K)
{
    __shared__ _Float16 Ah[128 * 64];
    __shared__ _Float16 Al[128 * 64];
    __shared__ _Float16 Wh[128 * 64];
    __shared__ _Float16 Wl[128 * 64];
    const int t = threadIdx.x;
    const int lane = t & 63;
    const int w = t >> 6;
    const int wr = w >> 1, wc = w & 1;
    const int row0 = blockIdx.y * 128, col0 = blockIdx.x * 128;

    // staging assignment: A: 2 segs x (1 row, 16 fp32); W: 1 row, 32 fp16 x2
    const int ar = t >> 2;            // rows ar and ar+64
    const int ak = (t & 3) * 16;      // fp32 col base
    const int wrow = t >> 1;
    const int wk = (t & 1) * 32;

    const float*    Abase = A   + (size_t)(row0 + ar) * K + ak;
    const _Float16* Whb   = Whg + (size_t)(col0 + wrow) * K + wk;
    const _Float16* Wlb   = Wlg + (size_t)(col0 + wrow) * K + wk;

    float4 aR[2][4];
    f16x8 wRh[4], wRl[4];

    auto load_tile = [&](int k0) {
#pragma unroll
        for (int s = 0; s < 2; ++s)
#pragma unroll
            for (int j = 0; j < 4; ++j)
                aR[s][j] = *(const float4*)(Abase + (size_t)s * 64 * K + k0 + 4 * j);
#pragma unroll
        for (int j = 0; j < 4; ++j) {
            wRh[j] = *(const f16x8*)(Whb + k0 + 8 * j);
            wRl[j] = *(const f16x8*)(Wlb + k0 + 8 * j);
        }
    };

    f32x4 acc[4][4];
#pragma unroll
    for (int m = 0; m < 4; ++m)
#pragma unroll
        for (int n = 0; n < 4; ++n) acc[m][n] = (f32x4)0.f;

    const int NT = K >> 6;
    load_tile(0);
    for (int kt = 0; kt < NT; ++kt) {
        __syncthreads();
        // ---- write staged tile to LDS (A converted fp32 -> hi/lo) --------
#pragma unroll
        for (int s = 0; s < 2; ++s) {
            const int row = ar + s * 64;
            const int sw = (row & 7) << 3;
            f16x8 hv[2], lv[2];
#pragma unroll
            for (int j = 0; j < 4; ++j) {
                const float4 v = aR[s][j];
                f16x8& H = hv[j >> 1];
                f16x8& L = lv[j >> 1];
                const int p = (j & 1) * 4;
                _Float16 h0 = (_Float16)v.x; H[p + 0] = h0; L[p + 0] = (_Float16)(v.x - (float)h0);
                _Float16 h1 = (_Float16)v.y; H[p + 1] = h1; L[p + 1] = (_Float16)(v.y - (float)h1);
                _Float16 h2 = (_Float16)v.z; H[p + 2] = h2; L[p + 2] = (_Float16)(v.z - (float)h2);
                _Float16 h3 = (_Float16)v.w; H[p + 3] = h3; L[p + 3] = (_Float16)(v.w - (float)h3);
            }
            const int eb = row * 64;
            *(f16x8*)&Ah[eb + ((ak + 0) ^ sw)] = hv[0];
            *(f16x8*)&Ah[eb + ((ak + 8) ^ sw)] = hv[1];
            *(f16x8*)&Al[eb + ((ak + 0) ^ sw)] = lv[0];
            *(f16x8*)&Al[eb + ((ak + 8) ^ sw)] = lv[1];
        }
        {
            const int sw = (wrow & 7) << 3;
            const int eb = wrow * 64;
#pragma unroll
            for (int j = 0; j < 4; ++j) {
                *(f16x8*)&Wh[eb + ((wk + 8 * j) ^ sw)] = wRh[j];
                *(f16x8*)&Wl[eb + ((wk + 8 * j) ^ sw)] = wRl[j];
            }
        }
        __syncthreads();
        if (kt + 1 < NT) load_tile((kt + 1) << 6);   // overlap w/ compute
        // ---- compute ------------------------------------------------------
#pragma unroll
        for (int ks = 0; ks < 2; ++ks) {
            const int kf = ks * 32 + (lane >> 4) * 8;
            f16x8 afh[4], afl[4], bfh[4], bfl[4];
#pragma unroll
            for (int m = 0; m < 4; ++m) {
                const int row = wr * 64 + m * 16 + (lane & 15);
                const int e = row * 64 + (kf ^ ((row & 7) << 3));
                afh[m] = *(const f16x8*)&Ah[e];
                afl[m] = *(const f16x8*)&Al[e];
            }
#pragma unroll
            for (int n = 0; n < 4; ++n) {
                const int row = wc * 64 + n * 16 + (lane & 15);
                const int e = row * 64 + (kf ^ ((row & 7) << 3));
                bfh[n] = *(const f16x8*)&Wh[e];
                bfl[n] = *(const f16x8*)&Wl[e];
            }
#pragma unroll
            for (int m = 0; m < 4; ++m)
#pragma unroll
                for (int n = 0; n < 4; ++n) {
                    acc[m][n] = __builtin_amdgcn_mfma_f32_16x16x32_f16(afh[m], bfh[n], acc[m][n], 0, 0, 0);
                    acc[m][n] = __builtin_amdgcn_mfma_f32_16x16x32_f16(afh[m], bfl[n], acc[m][n], 0, 0, 0);
                    acc[m][n] = __builtin_amdgcn_mfma_f32_16x16x32_f16(afl[m], bfh[n], acc[m][n], 0, 0, 0);
                }
        }
    }
    // ---- epilogue: bias (+ReLU), fp32 store --------------------------------
#pragma unroll
    for (int m = 0; m < 4; ++m) {
        const int rowc = row0 + wr * 64 + m * 16 + ((lane >> 4) << 2);
#pragma unroll
        for (int n = 0; n < 4; ++n) {
            const int colc = col0 + wc * 64 + n * 16 + (lane & 15);
            const float bv = bias[colc];
#pragma unroll
            for (int j = 0; j < 4; ++j) {
                float v = acc[m][n][j] + bv;
                if (RELU) v = fmaxf(v, 0.f);
                C[(size_t)(rowc + j) * N + colc] = v;
            }
        }
    }
}

// ---------------- fp32 GEMM (kept for the tiny head projections) -----------
template<int RELU>
__global__ __launch_bounds__(256) void gemm_bias(const float* __restrict__ A,
        const float* __restrict__ W, const float* __restrict__ bias,
        float* __restrict__ C, int M, int N, int K)
{
    __shared__ float As[8][128];
    __shared__ float Ws[8][128];
    const int tid = threadIdx.x;
    const int tn = tid & 15, tm = tid >> 4;
    const int row0 = blockIdx.y * 128, col0 = blockIdx.x * 128;
    const int lr = tid >> 1, lc = (tid & 1) * 4;
    const float* Ap = A + (size_t)(row0 + lr) * K + lc;
    const float* Wp = W + (size_t)(col0 + lr) * K + lc;
    float acc[8][8];
#pragma unroll
    for (int i = 0; i < 8; ++i)
#pragma unroll
        for (int j = 0; j < 8; ++j) acc[i][j] = 0.f;

    for (int k0 = 0; k0 < K; k0 += 8) {
        float4 av = *(const float4*)(Ap + k0);
        float4 wv = *(const float4*)(Wp + k0);
        __syncthreads();
        As[lc + 0][lr] = av.x; As[lc + 1][lr] = av.y;
        As[lc + 2][lr] = av.z; As[lc + 3][lr] = av.w;
        Ws[lc + 0][lr] = wv.x; Ws[lc + 1][lr] = wv.y;
        Ws[lc + 2][lr] = wv.z; Ws[lc + 3][lr] = wv.w;
        __syncthreads();
#pragma unroll
        for (int k = 0; k < 8; ++k) {
            float ar[8], wr[8];
#pragma unroll
            for (int i = 0; i < 8; ++i) ar[i] = As[k][tm * 8 + i];
#pragma unroll
            for (int j = 0; j < 8; ++j) wr[j] = Ws[k][tn * 8 + j];
#pragma unroll
            for (int i = 0; i < 8; ++i)
#pragma unroll
                for (int j = 0; j < 8; ++j)
                    acc[i][j] = fmaf(ar[i], wr[j], acc[i][j]);
        }
    }
#pragma unroll
    for (int i = 0; i < 8; ++i) {
        const int r = row0 + tm * 8 + i;
#pragma unroll
        for (int j = 0; j < 8; ++j) {
            const int c = col0 + tn * 8 + j;
            float v = acc[i][j] + bias[c];
            if (RELU) v = fmaxf(v, 0.f);
            C[(size_t)r * N + c] = v;
        }
    }
}

// ---------------- Attention: one block per (b,h), one thread per query row --
__global__ __launch_bounds__(128) void attn_kernel(const float* __restrict__ qkv,
                                                   float* __restrict__ o)
{
    const int bh = blockIdx.x;
    const int b = bh >> 3, hh = bh & 7;
    const int t = threadIdx.x;  // query row 0..127
    __shared__ float Ks[S_LEN][HD];
    __shared__ float Vs[S_LEN][HD];
    const float* base = qkv + (size_t)b * S_LEN * (3 * D_MODEL);
    const float* krow = base + (size_t)t * (3 * D_MODEL) + D_MODEL + hh * HD;
    const float* vrow = base + (size_t)t * (3 * D_MODEL) + 2 * D_MODEL + hh * HD;
#pragma unroll
    for (int d = 0; d < HD; d += 4) {
        *(float4*)&Ks[t][d] = *(const float4*)(krow + d);
        *(float4*)&Vs[t][d] = *(const float4*)(vrow + d);
    }
    float q[HD];
    const float* qrow = base + (size_t)t * (3 * D_MODEL) + hh * HD;
#pragma unroll
    for (int d = 0; d < HD; d += 4) {
        float4 v4 = *(const float4*)(qrow + d);
        q[d] = v4.x; q[d + 1] = v4.y; q[d + 2] = v4.z; q[d + 3] = v4.w;
    }
    __syncthreads();
    float m = -1e30f, l = 0.f;
    float oacc[HD];
#pragma unroll
    for (int d = 0; d < HD; ++d) oacc[d] = 0.f;
    for (int j = 0; j < S_LEN; ++j) {
        float s = 0.f;
#pragma unroll
        for (int d = 0; d < HD; ++d) s = fmaf(q[d], Ks[j][d], s);
        s *= 0.125f;
        const float nm = fmaxf(m, s);
        const float sc = expf(m - nm);
        const float p = expf(s - nm);
        l = l * sc + p;
#pragma unroll
        for (int d = 0; d < HD; ++d) oacc[d] = oacc[d] * sc + p * Vs[j][d];
        m = nm;
    }
    const float inv = 1.f / l;
    float* orow = o + (size_t)b * S_LEN * D_MODEL + (size_t)t * D_MODEL + hh * HD;
#pragma unroll
    for (int d = 0; d < HD; ++d) orow[d] = oacc[d] * inv;
}

// ---------------- residual add + LayerNorm (row of 512), 128 threads -------
__global__ __launch_bounds__(128) void add_ln_kernel(const float* __restrict__ a,
        const float* __restrict__ bb, const float* __restrict__ g,
        const float* __restrict__ be, float* __restrict__ out)
{
    __shared__ float red[2];
    const int row = blockIdx.x, t = threadIdx.x;
    float4 av = *(const float4*)(a + (size_t)row * D_MODEL + t * 4);
    float4 bv = *(const float4*)(bb + (size_t)row * D_MODEL + t * 4);
    float x0 = av.x + bv.x, x1 = av.y + bv.y, x2 = av.z + bv.z, x3 = av.w + bv.w;
    float ssum = x0 + x1 + x2 + x3;
#pragma unroll
    for (int off = 32; off >= 1; off >>= 1) ssum += __shfl_xor(ssum, off);
    if ((t & 63) == 0) red[t >> 6] = ssum;
    __syncthreads();
    const float mean = (red[0] + red[1]) * (1.f / 512.f);
    __syncthreads();
    float d0 = x0 - mean, d1 = x1 - mean, d2 = x2 - mean, d3 = x3 - mean;
    float sq = d0 * d0 + d1 * d1 + d2 * d2 + d3 * d3;
#pragma unroll
    for (int off = 32; off >= 1; off >>= 1) sq += __shfl_xor(sq, off);
    if ((t & 63) == 0) red[t >> 6] = sq;
    __syncthreads();
    const float var = (red[0] + red[1]) * (1.f / 512.f);
    const float inv = 1.0f / sqrtf(var + 1e-5f);
    float4 gv = *(const float4*)(g + t * 4);
    float4 bev = *(const float4*)(be + t * 4);
    float4 ov = make_float4(d0 * inv * gv.x + bev.x, d1 * inv * gv.y + bev.y,
                            d2 * inv * gv.z + bev.z, d3 * inv * gv.w + bev.w);
    *(float4*)(out + (size_t)row * D_MODEL + t * 4) = ov;
}

// ---------------- mean over sequence ---------------------------------------
__global__ __launch_bounds__(128) void pool_kernel(const float* __restrict__ x,
                                                   float* __restrict__ pooled)
{
    const int b = blockIdx.x, t = threadIdx.x;
    float4 acc = make_float4(0.f, 0.f, 0.f, 0.f);
    const float* base = x + (size_t)b * S_LEN * D_MODEL + t * 4;
    for (int s = 0; s < S_LEN; ++s) {
        float4 v = *(const float4*)(base + (size_t)s * D_MODEL);
        acc.x += v.x; acc.y += v.y; acc.z += v.z; acc.w += v.w;
    }
    const float sc = 1.f / 128.f;
    float4 ov = make_float4(acc.x * sc, acc.y * sc, acc.z * sc, acc.w * sc);
    *(float4*)(pooled + (size_t)b * D_MODEL + t * 4) = ov;
}

// ---------------- root-MUSIC: one 64-lane block per (batch, x/y) -----------
__global__ __launch_bounds__(64) void music_kernel(const float* __restrict__ RxRy,
                                                   float* __restrict__ hbuf)
{
    const int pb = blockIdx.x;          // 0..511
    const int b = pb >> 1, which = pb & 1;
    const float* src = RxRy + (size_t)which * (B_SZ * 128) + (size_t)b * 128;
    const int t = threadIdx.x;

    __shared__ double KRe[8][8], KIm[8][8];
    __shared__ double Are[8][8], Aim[8][8];
    __shared__ double Vre[8][8], Vim[8][8];
    __shared__ double Fre[8][8], Fim[8][8];
    __shared__ double rot[4];
    __shared__ double cr[15], ci[15];
    __shared__ double br[14], bi[14];
    __shared__ double zr[14], zi[14];
    __shared__ int topidx[3];

    {   // load K = complex(Rx[:8], Rx[8:])
        const int i = t >> 3, j = t & 7;
        KRe[i][j] = (double)src[i * 8 + j];
        KIm[i][j] = (double)src[64 + i * 8 + j];
    }
    __syncthreads();
    {   // Rz = K^H K + I ; V = I
        const int i = t >> 3, k = t & 7;
        double sre = (i == k) ? 1.0 : 0.0, sim = 0.0;
        for (int j = 0; j < 8; ++j) {
            const double ar = KRe[j][i], ai = KIm[j][i];
            const double xr = KRe[j][k], xi = KIm[j][k];
            sre += ar * xr + ai * xi;
            sim += ar * xi - ai * xr;
        }
        Are[i][k] = sre; Aim[i][k] = sim;
        Vre[i][k] = (i == k) ? 1.0 : 0.0;
        Vim[i][k] = 0.0;
    }
    __syncthreads();

    // cyclic complex Jacobi, 9 sweeps
    for (int sweep = 0; sweep < 9; ++sweep) {
        for (int p = 0; p < 7; ++p) {
            for (int q = p + 1; q < 8; ++q) {
                if (t == 0) {
                    const double gre = Are[p][q], gim = Aim[p][q];
                    const double r = sqrt(gre * gre + gim * gim);
                    if (r < 1e-60) {
                        rot[0] = 1.0; rot[1] = 0.0; rot[2] = 1.0; rot[3] = 0.0;
                    } else {
                        const double tau = (Are[p][p] - Are[q][q]) / (2.0 * r);
                        const double tt = ((tau >= 0.0) ? 1.0 : -1.0) /
                                          (fabs(tau) + sqrt(1.0 + tau * tau));
                        const double c = 1.0 / sqrt(1.0 + tt * tt);
                        rot[0] = c; rot[1] = tt * c; rot[2] = gre / r; rot[3] = gim / r;
                    }
                }
                __syncthreads();
                const double c = rot[0], s = rot[1], er = rot[2], ei = rot[3];
                if (t < 8) {  // column update on A and V  (A <- A U, V <- V U)
                    const int k = t;
                    double apr = Are[k][p], api = Aim[k][p];
                    double aqr = Are[k][q], aqi = Aim[k][q];
                    Are[k][p] = c * apr + s * (er * aqr + ei * aqi);
                    Aim[k][p] = c * api + s * (er * aqi - ei * aqr);
                    Are[k][q] = c * aqr - s * (er * apr - ei * api);
                    Aim[k][q] = c * aqi - s * (er * api + ei * apr);
                    double vpr = Vre[k][p], vpi = Vim[k][p];
                    double vqr = Vre[k][q], vqi = Vim[k][q];
                    Vre[k][p] = c * vpr + s * (er * vqr + ei * vqi);
                    Vim[k][p] = c * vpi + s * (er * vqi - ei * vqr);
                    Vre[k][q] = c * vqr - s * (er * vpr - ei * vpi);
                    Vim[k][q] = c * vqi - s * (er * vpi + ei * vpr);
                }
                __syncthreads();
                if (t < 8) {  // row update (A <- U^H A)
                    const int k = t;
                    double apr = Are[p][k], api = Aim[p][k];
                    double aqr = Are[q][k], aqi = Aim[q][k];
                    Are[p][k] = c * apr + s * (er * aqr - ei * aqi);
                    Aim[p][k] = c * api + s * (er * aqi + ei * aqr);
                    Are[q][k] = c * aqr - s * (er * apr + ei * api);
                    Aim[q][k] = c * aqi - s * (er * api - ei * apr);
                }
                __syncthreads();
                if (t == 0) {
                    Are[p][q] = 0.0; Aim[p][q] = 0.0;
                    Are[q][p] = 0.0; Aim[q][p] = 0.0;
                    Aim[p][p] = 0.0; Aim[q][q] = 0.0;
                }
                __syncthreads();
            }
        }
    }

    if (t == 0) {  // indices of 3 largest eigenvalues (signal subspace)
        bool used[8] = {false, false, false, false, false, false, false, false};
        for (int tt = 0; tt < 3; ++tt) {
            double best = -1e300; int bidx = 0;
            for (int i = 0; i < 8; ++i)
                if (!used[i] && Are[i][i] > best) { best = Are[i][i]; bidx = i; }
            used[bidx] = true; topidx[tt] = bidx;
        }
    }
    __syncthreads();
    {   // F = I - sum_top3 v v^H  (noise projector)
        const int i = t >> 3, j = t & 7;
        double fre = (i == j) ? 1.0 : 0.0, fim = 0.0;
        for (int tt = 0; tt < 3; ++tt) {
            const int e = topidx[tt];
            const double vir = Vre[i][e], vii = Vim[i][e];
            const double vjr = Vre[j][e], vji = Vim[j][e];
            fre -= vir * vjr + vii * vji;
            fim -= vii * vjr - vir * vji;
        }
        Fre[i][j] = fre; Fim[i][j] = fim;
    }
    __syncthreads();
    if (t < 15) {  // coeffs: sum of diagonal at offset o = t-7  (F[r][r+o])
        const int o = t - 7;
        double sre = 0.0, sim = 0.0;
        for (int r = 0; r < 8; ++r) {
            const int cc = r + o;
            if (cc >= 0 && cc < 8) { sre += Fre[r][cc]; sim += Fim[r][cc]; }
        }
        cr[t] = sre; ci[t] = sim;
    }
    __syncthreads();
    if (t < 14) {  // monic normalize + init roots (0.4+0.9i)^(t+1)
        const double den = cr[0] * cr[0] + ci[0] * ci[0];
        const double nr = cr[t + 1], ni = ci[t + 1];
        br[t] = (nr * cr[0] + ni * ci[0]) / den;
        bi[t] = (ni * cr[0] - nr * ci[0]) / den;
        double zre_ = 1.0, zim_ = 0.0;
        for (int k = 0; k <= t; ++k) {
            const double a2 = zre_ * 0.4 - zim_ * 0.9;
            zim_ = zre_ * 0.9 + zim_ * 0.4;
            zre_ = a2;
        }
        zr[t] = zre_; zi[t] = zim_;
    }
    __syncthreads();
    for (int it = 0; it < 128; ++it) {  // Durand-Kerner, synchronous update
        double nzr = 0.0, nzi = 0.0;
        if (t < 14) {
            const double zre_ = zr[t], zim_ = zi[t];
            double wre = 1.0, wim = 0.0;  // monic Horner
            for (int j = 0; j < 14; ++j) {
                const double tr = wre * zre_ - wim * zim_ + br[j];
                wim = wre * zim_ + wim * zre_ + bi[j];
                wre = tr;
            }
            double dre = 1.0, dim = 0.0;
            for (int j = 0; j < 14; ++j) {
                if (j == t) continue;
                const double exr = zre_ - zr[j], exi = zim_ - zi[j];
                const double tr = dre * exr - dim * exi;
                dim = dre * exi + dim * exr;
                dre = tr;
            }
            const double dd = dre * dre + dim * dim;
            if (dd > 1e-260) {
                const double qre = (wre * dre + wim * dim) / dd;
                const double qim = (wim * dre - wre * dim) / dd;
                nzr = zre_ - qre; nzi = zim_ - qim;
            } else {
                nzr = zre_ + 1e-8; nzi = zim_ - 1e-8;
            }
        }
        __syncthreads();
        if (t < 14) { zr[t] = nzr; zi[t] = nzi; }
        __syncthreads();
    }
    if (t == 0) {  // keyv selection (3 smallest, stable on ties) -> doa
        double keyv[14]; bool used[14];
        for (int i = 0; i < 14; ++i) {
            const double mag = sqrt(zr[i] * zr[i] + zi[i] * zi[i]);
            keyv[i] = fabs(mag - 1.0) + ((mag < 1.0) ? 0.0 : 1e6);
            used[i] = false;
        }
        for (int tt = 0; tt < 3; ++tt) {
            double best = 1e300; int bidx = 0;
            for (int i = 0; i < 14; ++i)
                if (!used[i] && keyv[i] < best) { best = keyv[i]; bidx = i; }
            used[bidx] = true;
            const double ang = atan2(zi[bidx], zr[bidx]);
            double ratio = ang / PI_D;
            if (ratio > 1.0) ratio = 1.0;
            if (ratio < -1.0) ratio = -1.0;
            hbuf[(size_t)b * 6 + which * 3 + tt] = (float)asin(ratio);
        }
    }
}

// ---------------- final MLP 6->256->256->6, one block per batch ------------
__global__ __launch_bounds__(256) void mlp_kernel(const float* __restrict__ hbuf,
        const float* __restrict__ w1, const float* __restrict__ b1,
        const float* __restrict__ w2, const float* __restrict__ b2,
        const float* __restrict__ w3, const float* __restrict__ b3,
        float* __restrict__ outp)
{
    const int b = blockIdx.x, t = threadIdx.x;
    __shared__ float hin[8];
    __shared__ float h1[256];
    __shared__ float h2[256];
    if (t < 6) hin[t] = hbuf[b * 6 + t];
    __syncthreads();
    float acc = b1[t];
#pragma unroll
    for (int k = 0; k < 6; ++k) acc += hin[k] * w1[t * 6 + k];
    h1[t] = fmaxf(acc, 0.f);
    __syncthreads();
    float acc2 = b2[t];
    for (int k = 0; k < 256; ++k) acc2 += h1[k] * w2[t * 256 + k];
    h2[t] = fmaxf(acc2, 0.f);
    __syncthreads();
    if (t < 6) {
        float acc3 = b3[t];
        for (int k = 0; k < 256; ++k) acc3 += h2[k] * w3[t * 256 + k];
        if (t < 3) outp[b * 3 + t] = acc3;
        else       outp[B_SZ * 3 + b * 3 + (t - 3)] = acc3;
    }
}

// ---------------- host launcher --------------------------------------------
extern "C" void kernel_launch(void* const* d_in, const int* in_sizes, int n_in,
                              void* d_out, int out_size, void* d_ws, size_t ws_size,
                              hipStream_t stream)
{
    const float* x_in      = (const float*)d_in[0];   // (32768,512)
    const float* in_proj_w = (const float*)d_in[1];
    const float* in_proj_b = (const float*)d_in[2];
    const float* out_proj_w= (const float*)d_in[3];
    const float* out_proj_b= (const float*)d_in[4];
    const float* ln1_g     = (const float*)d_in[5];
    const float* ln1_b     = (const float*)d_in[6];
    const float* ffn_w1    = (const float*)d_in[7];
    const float* ffn_b1    = (const float*)d_in[8];
    const float* ffn_w2    = (const float*)d_in[9];
    const float* ffn_b2    = (const float*)d_in[10];
    const float* ln2_g     = (const float*)d_in[11];
    const float* ln2_b     = (const float*)d_in[12];
    const float* fcx_w     = (const float*)d_in[13];
    const float* fcx_b     = (const float*)d_in[14];
    const float* fcy_w     = (const float*)d_in[15];
    const float* fcy_b     = (const float*)d_in[16];
    const float* mlp_w1    = (const float*)d_in[17];
    const float* mlp_b1    = (const float*)d_in[18];
    const float* mlp_w2    = (const float*)d_in[19];
    const float* mlp_b2    = (const float*)d_in[20];
    const float* mlp_w3    = (const float*)d_in[21];
    const float* mlp_b3    = (const float*)d_in[22];

    // ---- workspace layout ------------------------------------------------
    // static: split weights (fp16 hi/lo pairs), 3,145,728 floats total
    const size_t N_IPW = 1536 * 512, N_OPW = 512 * 512;
    const size_t N_F1W = 2048 * 512, N_F2W = 512 * 2048;
    const size_t WCVT = (N_IPW + N_OPW + N_F1W + N_F2W);  // elems; *2 fp16 = *1 float
    float* ws = (float*)d_ws;
    _Float16* ipw_h = (_Float16*)ws;
    _Float16* ipw_l = ipw_h + N_IPW;
    _Float16* opw_h = ipw_l + N_IPW;
    _Float16* opw_l = opw_h + N_OPW;
    _Float16* f1w_h = opw_l + N_OPW;
    _Float16* f1w_l = f1w_h + N_F1W;
    _Float16* f2w_h = f1w_l + N_F1W;
    _Float16* f2w_l = f2w_h + N_F2W;
    float* dyn = ws + WCVT;

    // dynamic: chunked activations. footprint = 393216*c + 262144 floats
    const size_t ws_floats = ws_size / sizeof(float);
    int c = 256;
    while (c > 1 && (size_t)393216 * (size_t)c + 262144 + WCVT > ws_floats) c >>= 1;

    float* RA     = dyn;                              // 262144*c : qkv | ff1
    float* x1     = RA + (size_t)262144 * c;          // 65536*c
    float* ff2    = x1 + (size_t)65536 * c;           // 65536*c
    float* pooled = ff2 + (size_t)65536 * c;          // 131072
    float* RxRy   = pooled + 131072;                  // 65536
    float* hbuf   = RxRy + 65536;                     // 1536

    float* qkv = RA;
    float* o   = RA + (size_t)196608 * c;
    float* ff1 = RA;

    // ---- split the four big weight matrices once -------------------------
    cvt_split<<<(N_IPW / 4 + 255) / 256, 256, 0, stream>>>(in_proj_w,  ipw_h, ipw_l, N_IPW / 4);
    cvt_split<<<(N_OPW / 4 + 255) / 256, 256, 0, stream>>>(out_proj_w, opw_h, opw_l, N_OPW / 4);
    cvt_split<<<(N_F1W / 4 + 255) / 256, 256, 0, stream>>>(ffn_w1,     f1w_h, f1w_l, N_F1W / 4);
    cvt_split<<<(N_F2W / 4 + 255) / 256, 256, 0, stream>>>(ffn_w2,     f2w_h, f2w_l, N_F2W / 4);

    for (int b0 = 0; b0 < B_SZ; b0 += c) {
        const int Tc = c * S_LEN;
        const float* xc = x_in + (size_t)b0 * S_LEN * D_MODEL;

        // 1. qkv = x @ Wi^T + bi
        gemm_mfma<0><<<dim3(1536 / 128, Tc / 128), 256, 0, stream>>>(
            xc, ipw_h, ipw_l, in_proj_b, qkv, Tc, 3 * D_MODEL, D_MODEL);
        // 2. attention
        attn_kernel<<<c * NHEADS, 128, 0, stream>>>(qkv, o);
        // 3. out proj
        gemm_mfma<0><<<dim3(512 / 128, Tc / 128), 256, 0, stream>>>(
            o, opw_h, opw_l, out_proj_b, x1, Tc, D_MODEL, D_MODEL);
        // 4. x1 = LN(x + proj)
        add_ln_kernel<<<Tc, 128, 0, stream>>>(xc, x1, ln1_g, ln1_b, x1);
        // 5. ff1 = relu(x1 @ W1^T + b1)
        gemm_mfma<1><<<dim3(DFFN / 128, Tc / 128), 256, 0, stream>>>(
            x1, f1w_h, f1w_l, ffn_b1, ff1, Tc, DFFN, D_MODEL);
        // 6. ff2 = ff1 @ W2^T + b2
        gemm_mfma<0><<<dim3(512 / 128, Tc / 128), 256, 0, stream>>>(
            ff1, f2w_h, f2w_l, ffn_b2, ff2, Tc, D_MODEL, DFFN);
        // 7. x2 = LN(x1 + ff2)
        add_ln_kernel<<<Tc, 128, 0, stream>>>(x1, ff2, ln2_g, ln2_b, x1);
        // 8. mean pool
        pool_kernel<<<c, 128, 0, stream>>>(x1, pooled + (size_t)b0 * D_MODEL);
    }

    // 9. heads (tiny)
    gemm_bias<0><<<dim3(1, 2), 256, 0, stream>>>(
        pooled, fcx_w, fcx_b, RxRy, B_SZ, 128, D_MODEL);
    gemm_bias<0><<<dim3(1, 2), 256, 0, stream>>>(
        pooled, fcy_w, fcy_b, RxRy + B_SZ * 128, B_SZ, 128, D_MODEL);
    // 10. root-MUSIC (fp64)
    music_kernel<<<2 * B_SZ, 64, 0, stream>>>(RxRy, hbuf);
    // 11. final MLP
    mlp_kernel<<<B_SZ, 256, 0, stream>>>(hbuf, mlp_w1, mlp_b1, mlp_w2, mlp_b2,
                                         mlp_w3, mlp_b3, (float*)d_out);
}